// Round 1
// baseline (5911.710 us; speedup 1.0000x reference)
//
#include <hip/hip_runtime.h>
#include <math.h>

#define BB 4096
#define HH 1024
#define RR 10
#define MIDD 512
#define D3 3072

// ---------------- reduction helpers ----------------
__device__ __forceinline__ float waveSum(float v){
#pragma unroll
  for(int o=32;o>0;o>>=1) v += __shfl_down(v,o,64);
  return v;
}
// blockDim.x == 256 only
__device__ __forceinline__ float blockSum256(float v, float* sc){
  v = waveSum(v);
  __syncthreads();
  if((threadIdx.x & 63)==0) sc[threadIdx.x>>6] = v;
  __syncthreads();
  return sc[0]+sc[1]+sc[2]+sc[3];
}
__device__ __forceinline__ float gelu_f(float x){
  return 0.5f*x*(1.0f+erff(x*0.70710678118654752f));
}

// ---------------- GEMM inner micro-kernel (shared by all tiled GEMMs) -------
#define GEMM_INNER \
  _Pragma("unroll") \
  for(int kk=0;kk<16;kk++){ \
    float4 a4=*(const float4*)&As[kk][ty*4]; \
    float4 b4=*(const float4*)&Ws[kk][tx*4]; \
    acc[0][0]=fmaf(a4.x,b4.x,acc[0][0]); acc[0][1]=fmaf(a4.x,b4.y,acc[0][1]); \
    acc[0][2]=fmaf(a4.x,b4.z,acc[0][2]); acc[0][3]=fmaf(a4.x,b4.w,acc[0][3]); \
    acc[1][0]=fmaf(a4.y,b4.x,acc[1][0]); acc[1][1]=fmaf(a4.y,b4.y,acc[1][1]); \
    acc[1][2]=fmaf(a4.y,b4.z,acc[1][2]); acc[1][3]=fmaf(a4.y,b4.w,acc[1][3]); \
    acc[2][0]=fmaf(a4.z,b4.x,acc[2][0]); acc[2][1]=fmaf(a4.z,b4.y,acc[2][1]); \
    acc[2][2]=fmaf(a4.z,b4.z,acc[2][2]); acc[2][3]=fmaf(a4.z,b4.w,acc[2][3]); \
    acc[3][0]=fmaf(a4.w,b4.x,acc[3][0]); acc[3][1]=fmaf(a4.w,b4.y,acc[3][1]); \
    acc[3][2]=fmaf(a4.w,b4.z,acc[3][2]); acc[3][3]=fmaf(a4.w,b4.w,acc[3][3]); \
  }

// ---------------- per-row stats for gate-go LN (rows = B*3) ----------------
__global__ void stats_go_k(const float* __restrict__ tokens, const int* __restrict__ mask,
                           float* __restrict__ stats){
  int row = blockIdx.x; int b = row/3; int j = row - b*3; int oj = (j==0)?0:(j+1);
  const float* to = tokens + ((size_t)b*4+oj)*HH;
  const float* ta = tokens + ((size_t)b*4+1)*HH;
  float mo = mask[b*4+oj] ? 1.f : 0.f;
  float s=0.f, s2=0.f;
  for(int k=threadIdx.x;k<HH;k+=256){
    float o=to[k]*mo, a=ta[k], d=fabsf(o-a);
    s += o+a+d; s2 += o*o+a*a+d*d;
  }
  __shared__ float sc[4];
  s = blockSum256(s, sc);
  s2 = blockSum256(s2, sc);
  if(threadIdx.x==0){
    float mean = s/(float)D3;
    float var  = s2/(float)D3 - mean*mean;
    stats[row*2]   = mean;
    stats[row*2+1] = rsqrtf(var+1e-5f);
  }
}

// ---------------- per-row stats for gate-ga LN (rows = B) ------------------
__global__ void stats_ga_k(const float* __restrict__ tokens, const float* __restrict__ omean,
                           float* __restrict__ stats){
  int b = blockIdx.x;
  const float* ta = tokens + ((size_t)b*4+1)*HH;
  const float* so = omean + (size_t)b*HH;
  float s=0.f, s2=0.f;
  for(int k=threadIdx.x;k<HH;k+=256){
    float a=ta[k], o=so[k], d=fabsf(a-o);
    s += a+o+d; s2 += a*a+o*o+d*d;
  }
  __shared__ float sc[4];
  s = blockSum256(s, sc);
  s2 = blockSum256(s2, sc);
  if(threadIdx.x==0){
    float mean = s/(float)D3;
    float var  = s2/(float)D3 - mean*mean;
    stats[b*2]   = mean;
    stats[b*2+1] = rsqrtf(var+1e-5f);
  }
}

// ---------------- generic NT GEMM: C = act(A @ W^T + bias) ------------------
// A: M x K row-major (lda), W: N x K row-major, C: M x N (ldc). 64x64 tiles.
template<int ACT>
__global__ void gemm_nt_k(const float* __restrict__ A, int lda,
                          const float* __restrict__ W, const float* __restrict__ bias,
                          float* __restrict__ C, int ldc, int K){
  __shared__ __align__(16) float As[16][68];
  __shared__ __align__(16) float Ws[16][68];
  int tid=threadIdx.x, tx=tid&15, ty=tid>>4;
  int row0=blockIdx.y*64, col0=blockIdx.x*64;
  int lr=tid>>2, lk=(tid&3)*4;
  const float* Ar = A + (size_t)(row0+lr)*lda;
  const float* Wr = W + (size_t)(col0+lr)*K;
  float acc[4][4]={};
  for(int k0=0;k0<K;k0+=16){
    float4 av=*(const float4*)(Ar+k0+lk);
    float4 wv=*(const float4*)(Wr+k0+lk);
    __syncthreads();
    As[lk+0][lr]=av.x; As[lk+1][lr]=av.y; As[lk+2][lr]=av.z; As[lk+3][lr]=av.w;
    Ws[lk+0][lr]=wv.x; Ws[lk+1][lr]=wv.y; Ws[lk+2][lr]=wv.z; Ws[lk+3][lr]=wv.w;
    __syncthreads();
    GEMM_INNER
  }
#pragma unroll
  for(int i=0;i<4;i++){
    int r=row0+ty*4+i;
#pragma unroll
    for(int j=0;j<4;j++){
      int c=col0+tx*4+j;
      float v=acc[i][j];
      if(ACT==1){ v+=bias[c]; v=gelu_f(v); }
      C[(size_t)r*ldc+c]=v;
    }
  }
}

// ------------- gate GEMM with fused feature construction + LN ---------------
// MODE 0: rows = B*3 (others-gate): t = tokens[b,oidx[j]]*mask, s = audio
// MODE 1: rows = B    (audio-gate):  t = audio,               s = others_mean
// Computes H = gelu(LN(feat) @ W1^T + b1), N = 512, K = 3072.
template<int MODE>
__global__ void gemm_gate_k(const float* __restrict__ tokens, const int* __restrict__ mask,
                            const float* __restrict__ omean, const float* __restrict__ stats,
                            const float* __restrict__ lnw, const float* __restrict__ lnb,
                            const float* __restrict__ W1, const float* __restrict__ b1,
                            float* __restrict__ Hout){
  __shared__ __align__(16) float As[16][68];
  __shared__ __align__(16) float Ws[16][68];
  int tid=threadIdx.x, tx=tid&15, ty=tid>>4;
  int row0=blockIdx.y*64, col0=blockIdx.x*64;
  int lr=tid>>2, lk=(tid&3)*4;
  int row=row0+lr;
  const float* tptr; const float* sptr; float tscale;
  if(MODE==0){
    int b=row/3; int j=row-b*3; int oj=(j==0)?0:(j+1);
    tptr = tokens + ((size_t)b*4+oj)*HH;
    sptr = tokens + ((size_t)b*4+1)*HH;
    tscale = mask[b*4+oj] ? 1.f : 0.f;
  } else {
    int b=row;
    tptr = tokens + ((size_t)b*4+1)*HH;
    sptr = omean + (size_t)b*HH;
    tscale = 1.f;
  }
  float mean=stats[row*2], rstd=stats[row*2+1];
  const float* Wr = W1 + (size_t)(col0+lr)*D3;
  float acc[4][4]={};
  for(int k0=0;k0<D3;k0+=16){
    int k=k0+lk;
    float4 v;
    if(k<HH){
      float4 o=*(const float4*)(tptr+k);
      v=make_float4(o.x*tscale,o.y*tscale,o.z*tscale,o.w*tscale);
    } else if(k<2*HH){
      v=*(const float4*)(sptr+(k-HH));
    } else {
      float4 o=*(const float4*)(tptr+(k-2*HH));
      float4 a=*(const float4*)(sptr+(k-2*HH));
      v=make_float4(fabsf(o.x*tscale-a.x),fabsf(o.y*tscale-a.y),
                    fabsf(o.z*tscale-a.z),fabsf(o.w*tscale-a.w));
    }
    float4 w4=*(const float4*)(lnw+k);
    float4 b4=*(const float4*)(lnb+k);
    v.x=(v.x-mean)*rstd*w4.x+b4.x;
    v.y=(v.y-mean)*rstd*w4.y+b4.y;
    v.z=(v.z-mean)*rstd*w4.z+b4.z;
    v.w=(v.w-mean)*rstd*w4.w+b4.w;
    float4 wv=*(const float4*)(Wr+k);
    __syncthreads();
    As[lk+0][lr]=v.x; As[lk+1][lr]=v.y; As[lk+2][lr]=v.z; As[lk+3][lr]=v.w;
    Ws[lk+0][lr]=wv.x; Ws[lk+1][lr]=wv.y; Ws[lk+2][lr]=wv.z; Ws[lk+3][lr]=wv.w;
    __syncthreads();
    GEMM_INNER
  }
#pragma unroll
  for(int i=0;i<4;i++){
    int r=row0+ty*4+i;
#pragma unroll
    for(int j=0;j<4;j++){
      int c=col0+tx*4+j;
      float v=acc[i][j]+b1[c];
      Hout[(size_t)r*MIDD+c]=gelu_f(v);
    }
  }
}

// ---------------- gate reduce: g = sigmoid(H . w2 + b2) ---------------------
__global__ void gate_reduce_k(const float* __restrict__ Hx, const float* __restrict__ w2,
                              const float* __restrict__ b2, float* __restrict__ g, int cols){
  int row=blockIdx.x;
  float s=0.f;
  for(int c=threadIdx.x;c<cols;c+=64) s += Hx[(size_t)row*cols+c]*w2[c];
  s=waveSum(s);
  if(threadIdx.x==0) g[row]=1.f/(1.f+expf(-(s+b2[0])));
}

// ------- others_new (into mixed slots 0,2,3) + others_mean ------------------
__global__ void others_k(const float* __restrict__ tokens, const int* __restrict__ mask,
                         const float* __restrict__ g, const float* __restrict__ a2o,
                         const float* __restrict__ lnw, const float* __restrict__ lnb,
                         float* __restrict__ mixed, float* __restrict__ omean){
  int b=blockIdx.x, tid=threadIdx.x;
  __shared__ float sc[4];
  float ma = mask[b*4+1]?1.f:0.f;
  float a2[4];
#pragma unroll
  for(int p=0;p<4;p++) a2[p]=a2o[(size_t)b*HH+tid+p*256];
  float sum[4]={0,0,0,0}; float cnt=0.f;
  for(int j=0;j<3;j++){
    int oj=(j==0)?0:(j+1);
    float mo=mask[b*4+oj]?1.f:0.f; cnt+=mo;
    float gv=g[b*3+j];
    float t[4], ov[4]; float s=0.f,s2=0.f;
#pragma unroll
    for(int p=0;p<4;p++){
      int h=tid+p*256;
      float o=tokens[((size_t)b*4+oj)*HH+h]*mo;
      ov[p]=o; t[p]=o+gv*a2[p];
      s+=t[p]; s2+=t[p]*t[p];
    }
    s=blockSum256(s,sc); s2=blockSum256(s2,sc);
    float mean=s/1024.f, rstd=rsqrtf(s2/1024.f-mean*mean+1e-5f);
    float pv=mo*ma;
#pragma unroll
    for(int p=0;p<4;p++){
      int h=tid+p*256;
      float upd=(t[p]-mean)*rstd*lnw[h]+lnb[h];
      float on=((pv>0.5f)?upd:ov[p])*mo;
      mixed[(size_t)b*4096 + (size_t)oj*HH + h]=on;
      sum[p]+=on*mo;
    }
  }
  float denom=fmaxf(cnt,1.f);
#pragma unroll
  for(int p=0;p<4;p++) omean[(size_t)b*HH+tid+p*256]=sum[p]/denom;
}

// ---------------- mixed_audio (into mixed slot 1) ---------------------------
__global__ void audio_k(const float* __restrict__ tokens, const int* __restrict__ mask,
                        const float* __restrict__ g_a, const float* __restrict__ o2a,
                        const float* __restrict__ lnw, const float* __restrict__ lnb,
                        float* __restrict__ mixed){
  int b=blockIdx.x, tid=threadIdx.x;
  __shared__ float sc[4];
  int ma_i=mask[b*4+1];
  int any = mask[b*4+0]|mask[b*4+2]|mask[b*4+3];
  bool aum = (ma_i!=0) && (any!=0);
  float ma = ma_i?1.f:0.f;
  float gv=g_a[b];
  const float* ta = tokens + ((size_t)b*4+1)*HH;
  float av[4], t[4]; float s=0.f,s2=0.f;
#pragma unroll
  for(int p=0;p<4;p++){
    int h=tid+p*256;
    av[p]=ta[h];
    t[p]=av[p]+gv*o2a[(size_t)b*HH+h];
    s+=t[p]; s2+=t[p]*t[p];
  }
  s=blockSum256(s,sc); s2=blockSum256(s2,sc);
  float mean=s/1024.f, rstd=rsqrtf(s2/1024.f-mean*mean+1e-5f);
#pragma unroll
  for(int p=0;p<4;p++){
    int h=tid+p*256;
    float u=(t[p]-mean)*rstd*lnw[h]+lnb[h];
    float outv = aum ? u : av[p]*ma;
    mixed[(size_t)b*4096 + HH + h]=outv*ma;
  }
}

// ---------------- P := 1 ----------------------------------------------------
__global__ void init_ones_k(float* __restrict__ P, size_t n){
  size_t i=(size_t)blockIdx.x*256+threadIdx.x;
  if(i<n) P[i]=1.f;
}

// -------- LMF GEMM: P[b,r,:] *= (mask[b,m] ? z[b,m,r,:] : 1) ----------------
// z = factors[m,r,0,:] + sum_d mixed[b,m,d]*factors[m,r,d+1,:]
__global__ void gemm_lmf_k(const float* __restrict__ mixed, const float* __restrict__ factors,
                           const int* __restrict__ mask, float* __restrict__ P, int m){
  __shared__ __align__(16) float As[16][68];
  __shared__ __align__(16) float Ws[16][68];
  int tid=threadIdx.x, tx=tid&15, ty=tid>>4;
  int row0=blockIdx.y*64, col0=blockIdx.x*64;
  int r=blockIdx.z;
  const float* F0 = factors + ((size_t)(m*RR+r)*1025)*HH;  // d = 0 row
  const float* B1 = F0 + HH;                               // d = 1.. rows
  int lr=tid>>2, lk=(tid&3)*4;   // A loader: 64 rows x 16 k
  int kb=tid>>4, nb=(tid&15)*4;  // B loader: 16 k x 64 n
  const float* Ar = mixed + (size_t)(row0+lr)*4096 + (size_t)m*HH;
  float acc[4][4]={};
  for(int k0=0;k0<HH;k0+=16){
    float4 av=*(const float4*)(Ar+k0+lk);
    float4 wv=*(const float4*)(B1+(size_t)(k0+kb)*HH+col0+nb);
    __syncthreads();
    As[lk+0][lr]=av.x; As[lk+1][lr]=av.y; As[lk+2][lr]=av.z; As[lk+3][lr]=av.w;
    *(float4*)&Ws[kb][nb]=wv;
    __syncthreads();
    GEMM_INNER
  }
#pragma unroll
  for(int i=0;i<4;i++){
    int b=row0+ty*4+i;
    int mk=mask[b*4+m];
#pragma unroll
    for(int j=0;j<4;j++){
      int c=col0+tx*4+j;
      float z=acc[i][j]+F0[c];
      float v = mk ? z : 1.f;
      size_t pi=((size_t)b*RR+r)*HH+c;
      P[pi]*=v;
    }
  }
}

// -------- fused[b,h] = sum_r rank_w[r]*P[b,r,h] + lmf_bias[h] ---------------
__global__ void fuse_k(const float* __restrict__ P, const float* __restrict__ rank_w,
                       const float* __restrict__ lmf_bias, float* __restrict__ fused){
  size_t i=(size_t)blockIdx.x*256+threadIdx.x;
  int b=(int)(i>>10), h=(int)(i&1023);
  float s=lmf_bias[h];
#pragma unroll
  for(int r=0;r<RR;r++) s += rank_w[r]*P[((size_t)b*RR+r)*HH+h];
  fused[i]=s;
}

// ---------------- row LayerNorm over H=1024 ---------------------------------
__global__ void ln_row_k(const float* __restrict__ X, const float* __restrict__ w,
                         const float* __restrict__ bb, float* __restrict__ Y){
  int b=blockIdx.x, tid=threadIdx.x;
  __shared__ float sc[4];
  const float* x=X+(size_t)b*HH;
  float t[4]; float s=0.f,s2=0.f;
#pragma unroll
  for(int p=0;p<4;p++){ t[p]=x[tid+p*256]; s+=t[p]; s2+=t[p]*t[p]; }
  s=blockSum256(s,sc); s2=blockSum256(s2,sc);
  float mean=s/1024.f, rstd=rsqrtf(s2/1024.f-mean*mean+1e-5f);
#pragma unroll
  for(int p=0;p<4;p++){
    int h=tid+p*256;
    Y[(size_t)b*HH+h]=(t[p]-mean)*rstd*w[h]+bb[h];
  }
}

// ---------------- launch ----------------------------------------------------
extern "C" void kernel_launch(void* const* d_in, const int* in_sizes, int n_in,
                              void* d_out, int out_size, void* d_ws, size_t ws_size,
                              hipStream_t stream) {
  const float* tokens   =(const float*)d_in[0];
  const int*   mask     =(const int*)  d_in[1];
  const float* ln_go_w  =(const float*)d_in[2];
  const float* ln_go_b  =(const float*)d_in[3];
  const float* go_w1    =(const float*)d_in[4];
  const float* go_b1    =(const float*)d_in[5];
  const float* go_w2    =(const float*)d_in[6];
  const float* go_b2    =(const float*)d_in[7];
  const float* ln_ga_w  =(const float*)d_in[8];
  const float* ln_ga_b  =(const float*)d_in[9];
  const float* ga_w1    =(const float*)d_in[10];
  const float* ga_b1    =(const float*)d_in[11];
  const float* ga_w2    =(const float*)d_in[12];
  const float* ga_b2    =(const float*)d_in[13];
  const float* a2o_w    =(const float*)d_in[14];
  const float* o2a_w    =(const float*)d_in[15];
  const float* ln_o_w   =(const float*)d_in[16];
  const float* ln_o_b   =(const float*)d_in[17];
  const float* ln_a_w   =(const float*)d_in[18];
  const float* ln_a_b   =(const float*)d_in[19];
  const float* factors  =(const float*)d_in[20];
  const float* rank_w   =(const float*)d_in[21];
  const float* lmf_bias =(const float*)d_in[22];
  const float* out_ln1_w=(const float*)d_in[23];
  const float* out_ln1_b=(const float*)d_in[24];
  const float* out_w    =(const float*)d_in[25];
  const float* out_b    =(const float*)d_in[26];
  const float* out_ln2_w=(const float*)d_in[27];
  const float* out_ln2_b=(const float*)d_in[28];
  float* out=(float*)d_out;

  char* wsp=(char*)d_ws; size_t off=0;
  auto alloc=[&](size_t bytes)->void*{
    void* p=wsp+off; off=(off+bytes+255)&~(size_t)255; return p;
  };
  float* stats_go=(float*)alloc((size_t)BB*3*2*4);
  float* H1      =(float*)alloc((size_t)BB*3*MIDD*4);
  float* g_go    =(float*)alloc((size_t)BB*3*4);
  float* a2o     =(float*)alloc((size_t)BB*HH*4);
  float* mixed   =(float*)alloc((size_t)BB*4*HH*4);
  float* omean   =(float*)alloc((size_t)BB*HH*4);
  float* stats_ga=(float*)alloc((size_t)BB*2*4);
  float* H2      =(float*)alloc((size_t)BB*MIDD*4);
  float* g_a     =(float*)alloc((size_t)BB*4);
  float* o2a     =(float*)alloc((size_t)BB*HH*4);
  float* P       =(float*)alloc((size_t)BB*RR*HH*4);
  float* fused   =(float*)alloc((size_t)BB*HH*4);
  float* hbuf    =(float*)alloc((size_t)BB*HH*4);

  // 1) gate-others LN stats
  stats_go_k<<<BB*3,256,0,stream>>>(tokens,mask,stats_go);
  // 2) a2o = audio @ a2o_w^T
  gemm_nt_k<0><<<dim3(HH/64,BB/64),256,0,stream>>>(tokens+HH,4*HH,a2o_w,nullptr,a2o,HH,HH);
  // 3) H1 = gelu(LN(feat_go) @ go_w1^T + go_b1)
  gemm_gate_k<0><<<dim3(MIDD/64,(BB*3)/64),256,0,stream>>>(tokens,mask,omean,stats_go,
                                                           ln_go_w,ln_go_b,go_w1,go_b1,H1);
  // 4) g_go = sigmoid(H1 . go_w2 + go_b2)
  gate_reduce_k<<<BB*3,64,0,stream>>>(H1,go_w2,go_b2,g_go,MIDD);
  // 5) others_new -> mixed slots {0,2,3}; others_mean
  others_k<<<BB,256,0,stream>>>(tokens,mask,g_go,a2o,ln_o_w,ln_o_b,mixed,omean);
  // 6) gate-audio LN stats
  stats_ga_k<<<BB,256,0,stream>>>(tokens,omean,stats_ga);
  // 7) H2 = gelu(LN(feat_ga) @ ga_w1^T + ga_b1)
  gemm_gate_k<1><<<dim3(MIDD/64,BB/64),256,0,stream>>>(tokens,mask,omean,stats_ga,
                                                       ln_ga_w,ln_ga_b,ga_w1,ga_b1,H2);
  // 8) g_a
  gate_reduce_k<<<BB,64,0,stream>>>(H2,ga_w2,ga_b2,g_a,MIDD);
  // 9) o2a = others_mean @ o2a_w^T
  gemm_nt_k<0><<<dim3(HH/64,BB/64),256,0,stream>>>(omean,HH,o2a_w,nullptr,o2a,HH,HH);
  // 10) mixed_audio -> mixed slot 1
  audio_k<<<BB,256,0,stream>>>(tokens,mask,g_a,o2a,ln_a_w,ln_a_b,mixed);
  // 11) P := 1
  init_ones_k<<<(BB*RR*HH)/256,256,0,stream>>>(P,(size_t)BB*RR*HH);
  // 12) rank product: 4 sequential per-m GEMM-multiplies
  for(int m=0;m<4;m++)
    gemm_lmf_k<<<dim3(HH/64,BB/64,RR),256,0,stream>>>(mixed,factors,mask,P,m);
  // 13) fused = sum_r rank_w[r]*P + lmf_bias
  fuse_k<<<(BB*HH)/256,256,0,stream>>>(P,rank_w,lmf_bias,fused);
  // 14) h = LN(fused)
  ln_row_k<<<BB,256,0,stream>>>(fused,out_ln1_w,out_ln1_b,hbuf);
  // 15) h = gelu(h @ out_w^T + out_b)
  gemm_nt_k<1><<<dim3(HH/64,BB/64),256,0,stream>>>(hbuf,HH,out_w,out_b,fused,HH,HH);
  // 16) out = LN(h)
  ln_row_k<<<BB,256,0,stream>>>(fused,out_ln2_w,out_ln2_b,out);
}

// Round 2
// 2317.132 us; speedup vs baseline: 2.5513x; 2.5513x over previous
//
#include <hip/hip_runtime.h>
#include <math.h>

#define BB 4096
#define HH 1024
#define RR 10
#define MIDD 512
#define D3 3072

typedef __bf16 bf16x8 __attribute__((ext_vector_type(8)));
typedef __bf16 bf16x4 __attribute__((ext_vector_type(4)));
typedef float f32x4 __attribute__((ext_vector_type(4)));

// ---------------- reduction helpers ----------------
__device__ __forceinline__ float waveSum(float v){
#pragma unroll
  for(int o=32;o>0;o>>=1) v += __shfl_down(v,o,64);
  return v;
}
__device__ __forceinline__ float blockSum256(float v, float* sc){
  v = waveSum(v);
  __syncthreads();
  if((threadIdx.x & 63)==0) sc[threadIdx.x>>6] = v;
  __syncthreads();
  return sc[0]+sc[1]+sc[2]+sc[3];
}
__device__ __forceinline__ float gelu_f(float x){
  return 0.5f*x*(1.0f+erff(x*0.70710678118654752f));
}

__device__ __forceinline__ void gl_lds16(const void* g, void* lds){
  __builtin_amdgcn_global_load_lds((const __attribute__((address_space(1))) unsigned int*)g,
                                   (__attribute__((address_space(3))) unsigned int*)lds,
                                   16, 0, 0);
}

// ---------------- GEMM inner micro-kernel (fp32 tiled GEMMs) -------
#define GEMM_INNER \
  _Pragma("unroll") \
  for(int kk=0;kk<16;kk++){ \
    float4 a4=*(const float4*)&As[kk][ty*4]; \
    float4 b4=*(const float4*)&Ws[kk][tx*4]; \
    acc[0][0]=fmaf(a4.x,b4.x,acc[0][0]); acc[0][1]=fmaf(a4.x,b4.y,acc[0][1]); \
    acc[0][2]=fmaf(a4.x,b4.z,acc[0][2]); acc[0][3]=fmaf(a4.x,b4.w,acc[0][3]); \
    acc[1][0]=fmaf(a4.y,b4.x,acc[1][0]); acc[1][1]=fmaf(a4.y,b4.y,acc[1][1]); \
    acc[1][2]=fmaf(a4.y,b4.z,acc[1][2]); acc[1][3]=fmaf(a4.y,b4.w,acc[1][3]); \
    acc[2][0]=fmaf(a4.z,b4.x,acc[2][0]); acc[2][1]=fmaf(a4.z,b4.y,acc[2][1]); \
    acc[2][2]=fmaf(a4.z,b4.z,acc[2][2]); acc[2][3]=fmaf(a4.z,b4.w,acc[2][3]); \
    acc[3][0]=fmaf(a4.w,b4.x,acc[3][0]); acc[3][1]=fmaf(a4.w,b4.y,acc[3][1]); \
    acc[3][2]=fmaf(a4.w,b4.z,acc[3][2]); acc[3][3]=fmaf(a4.w,b4.w,acc[3][3]); \
  }

// ---------------- per-row stats for gate-go LN (rows = B*3) ----------------
__global__ void stats_go_k(const float* __restrict__ tokens, const int* __restrict__ mask,
                           float* __restrict__ stats){
  int row = blockIdx.x; int b = row/3; int j = row - b*3; int oj = (j==0)?0:(j+1);
  const float* to = tokens + ((size_t)b*4+oj)*HH;
  const float* ta = tokens + ((size_t)b*4+1)*HH;
  float mo = mask[b*4+oj] ? 1.f : 0.f;
  float s=0.f, s2=0.f;
  for(int k=threadIdx.x;k<HH;k+=256){
    float o=to[k]*mo, a=ta[k], d=fabsf(o-a);
    s += o+a+d; s2 += o*o+a*a+d*d;
  }
  __shared__ float sc[4];
  s = blockSum256(s, sc);
  s2 = blockSum256(s2, sc);
  if(threadIdx.x==0){
    float mean = s/(float)D3;
    float var  = s2/(float)D3 - mean*mean;
    stats[row*2]   = mean;
    stats[row*2+1] = rsqrtf(var+1e-5f);
  }
}

// ---------------- per-row stats for gate-ga LN (rows = B) ------------------
__global__ void stats_ga_k(const float* __restrict__ tokens, const float* __restrict__ omean,
                           float* __restrict__ stats){
  int b = blockIdx.x;
  const float* ta = tokens + ((size_t)b*4+1)*HH;
  const float* so = omean + (size_t)b*HH;
  float s=0.f, s2=0.f;
  for(int k=threadIdx.x;k<HH;k+=256){
    float a=ta[k], o=so[k], d=fabsf(a-o);
    s += a+o+d; s2 += a*a+o*o+d*d;
  }
  __shared__ float sc[4];
  s = blockSum256(s, sc);
  s2 = blockSum256(s2, sc);
  if(threadIdx.x==0){
    float mean = s/(float)D3;
    float var  = s2/(float)D3 - mean*mean;
    stats[b*2]   = mean;
    stats[b*2+1] = rsqrtf(var+1e-5f);
  }
}

// ---------------- generic NT GEMM: C = act(A @ W^T + bias) ------------------
template<int ACT>
__global__ void gemm_nt_k(const float* __restrict__ A, int lda,
                          const float* __restrict__ W, const float* __restrict__ bias,
                          float* __restrict__ C, int ldc, int K){
  __shared__ __align__(16) float As[16][68];
  __shared__ __align__(16) float Ws[16][68];
  int tid=threadIdx.x, tx=tid&15, ty=tid>>4;
  int row0=blockIdx.y*64, col0=blockIdx.x*64;
  int lr=tid>>2, lk=(tid&3)*4;
  const float* Ar = A + (size_t)(row0+lr)*lda;
  const float* Wr = W + (size_t)(col0+lr)*K;
  float acc[4][4]={};
  for(int k0=0;k0<K;k0+=16){
    float4 av=*(const float4*)(Ar+k0+lk);
    float4 wv=*(const float4*)(Wr+k0+lk);
    __syncthreads();
    As[lk+0][lr]=av.x; As[lk+1][lr]=av.y; As[lk+2][lr]=av.z; As[lk+3][lr]=av.w;
    Ws[lk+0][lr]=wv.x; Ws[lk+1][lr]=wv.y; Ws[lk+2][lr]=wv.z; Ws[lk+3][lr]=wv.w;
    __syncthreads();
    GEMM_INNER
  }
#pragma unroll
  for(int i=0;i<4;i++){
    int r=row0+ty*4+i;
#pragma unroll
    for(int j=0;j<4;j++){
      int c=col0+tx*4+j;
      float v=acc[i][j];
      if(ACT==1){ v+=bias[c]; v=gelu_f(v); }
      C[(size_t)r*ldc+c]=v;
    }
  }
}

// ------------- gate GEMM with fused feature construction + LN ---------------
template<int MODE>
__global__ void gemm_gate_k(const float* __restrict__ tokens, const int* __restrict__ mask,
                            const float* __restrict__ omean, const float* __restrict__ stats,
                            const float* __restrict__ lnw, const float* __restrict__ lnb,
                            const float* __restrict__ W1, const float* __restrict__ b1,
                            float* __restrict__ Hout){
  __shared__ __align__(16) float As[16][68];
  __shared__ __align__(16) float Ws[16][68];
  int tid=threadIdx.x, tx=tid&15, ty=tid>>4;
  int row0=blockIdx.y*64, col0=blockIdx.x*64;
  int lr=tid>>2, lk=(tid&3)*4;
  int row=row0+lr;
  const float* tptr; const float* sptr; float tscale;
  if(MODE==0){
    int b=row/3; int j=row-b*3; int oj=(j==0)?0:(j+1);
    tptr = tokens + ((size_t)b*4+oj)*HH;
    sptr = tokens + ((size_t)b*4+1)*HH;
    tscale = mask[b*4+oj] ? 1.f : 0.f;
  } else {
    int b=row;
    tptr = tokens + ((size_t)b*4+1)*HH;
    sptr = omean + (size_t)b*HH;
    tscale = 1.f;
  }
  float mean=stats[row*2], rstd=stats[row*2+1];
  const float* Wr = W1 + (size_t)(col0+lr)*D3;
  float acc[4][4]={};
  for(int k0=0;k0<D3;k0+=16){
    int k=k0+lk;
    float4 v;
    if(k<HH){
      float4 o=*(const float4*)(tptr+k);
      v=make_float4(o.x*tscale,o.y*tscale,o.z*tscale,o.w*tscale);
    } else if(k<2*HH){
      v=*(const float4*)(sptr+(k-HH));
    } else {
      float4 o=*(const float4*)(tptr+(k-2*HH));
      float4 a=*(const float4*)(sptr+(k-2*HH));
      v=make_float4(fabsf(o.x*tscale-a.x),fabsf(o.y*tscale-a.y),
                    fabsf(o.z*tscale-a.z),fabsf(o.w*tscale-a.w));
    }
    float4 w4=*(const float4*)(lnw+k);
    float4 b4=*(const float4*)(lnb+k);
    v.x=(v.x-mean)*rstd*w4.x+b4.x;
    v.y=(v.y-mean)*rstd*w4.y+b4.y;
    v.z=(v.z-mean)*rstd*w4.z+b4.z;
    v.w=(v.w-mean)*rstd*w4.w+b4.w;
    float4 wv=*(const float4*)(Wr+k);
    __syncthreads();
    As[lk+0][lr]=v.x; As[lk+1][lr]=v.y; As[lk+2][lr]=v.z; As[lk+3][lr]=v.w;
    Ws[lk+0][lr]=wv.x; Ws[lk+1][lr]=wv.y; Ws[lk+2][lr]=wv.z; Ws[lk+3][lr]=wv.w;
    __syncthreads();
    GEMM_INNER
  }
#pragma unroll
  for(int i=0;i<4;i++){
    int r=row0+ty*4+i;
#pragma unroll
    for(int j=0;j<4;j++){
      int c=col0+tx*4+j;
      float v=acc[i][j]+b1[c];
      Hout[(size_t)r*MIDD+c]=gelu_f(v);
    }
  }
}

// ---------------- gate reduce: g = sigmoid(H . w2 + b2) ---------------------
__global__ void gate_reduce_k(const float* __restrict__ Hx, const float* __restrict__ w2,
                              const float* __restrict__ b2, float* __restrict__ g, int cols){
  int row=blockIdx.x;
  float s=0.f;
  for(int c=threadIdx.x;c<cols;c+=64) s += Hx[(size_t)row*cols+c]*w2[c];
  s=waveSum(s);
  if(threadIdx.x==0) g[row]=1.f/(1.f+expf(-(s+b2[0])));
}

// ------- others_new (into mixedB slots 0,2,3, bf16) + others_mean -----------
__global__ void others_k(const float* __restrict__ tokens, const int* __restrict__ mask,
                         const float* __restrict__ g, const float* __restrict__ a2o,
                         const float* __restrict__ lnw, const float* __restrict__ lnb,
                         __bf16* __restrict__ mixedB, float* __restrict__ omean){
  int b=blockIdx.x, tid=threadIdx.x;
  __shared__ float sc[4];
  float ma = mask[b*4+1]?1.f:0.f;
  float a2[4];
#pragma unroll
  for(int p=0;p<4;p++) a2[p]=a2o[(size_t)b*HH+tid+p*256];
  float sum[4]={0,0,0,0}; float cnt=0.f;
  for(int j=0;j<3;j++){
    int oj=(j==0)?0:(j+1);
    float mo=mask[b*4+oj]?1.f:0.f; cnt+=mo;
    float gv=g[b*3+j];
    float t[4], ov[4]; float s=0.f,s2=0.f;
#pragma unroll
    for(int p=0;p<4;p++){
      int h=tid+p*256;
      float o=tokens[((size_t)b*4+oj)*HH+h]*mo;
      ov[p]=o; t[p]=o+gv*a2[p];
      s+=t[p]; s2+=t[p]*t[p];
    }
    s=blockSum256(s,sc); s2=blockSum256(s2,sc);
    float mean=s/1024.f, rstd=rsqrtf(s2/1024.f-mean*mean+1e-5f);
    float pv=mo*ma;
#pragma unroll
    for(int p=0;p<4;p++){
      int h=tid+p*256;
      float upd=(t[p]-mean)*rstd*lnw[h]+lnb[h];
      float on=((pv>0.5f)?upd:ov[p])*mo;
      mixedB[(size_t)b*4096 + (size_t)oj*HH + h]=(__bf16)on;
      sum[p]+=on*mo;
    }
  }
  float denom=fmaxf(cnt,1.f);
#pragma unroll
  for(int p=0;p<4;p++) omean[(size_t)b*HH+tid+p*256]=sum[p]/denom;
}

// ---------------- mixed_audio (into mixedB slot 1, bf16) --------------------
__global__ void audio_k(const float* __restrict__ tokens, const int* __restrict__ mask,
                        const float* __restrict__ g_a, const float* __restrict__ o2a,
                        const float* __restrict__ lnw, const float* __restrict__ lnb,
                        __bf16* __restrict__ mixedB){
  int b=blockIdx.x, tid=threadIdx.x;
  __shared__ float sc[4];
  int ma_i=mask[b*4+1];
  int any = mask[b*4+0]|mask[b*4+2]|mask[b*4+3];
  bool aum = (ma_i!=0) && (any!=0);
  float ma = ma_i?1.f:0.f;
  float gv=g_a[b];
  const float* ta = tokens + ((size_t)b*4+1)*HH;
  float av[4], t[4]; float s=0.f,s2=0.f;
#pragma unroll
  for(int p=0;p<4;p++){
    int h=tid+p*256;
    av[p]=ta[h];
    t[p]=av[p]+gv*o2a[(size_t)b*HH+h];
    s+=t[p]; s2+=t[p]*t[p];
  }
  s=blockSum256(s,sc); s2=blockSum256(s2,sc);
  float mean=s/1024.f, rstd=rsqrtf(s2/1024.f-mean*mean+1e-5f);
#pragma unroll
  for(int p=0;p<4;p++){
    int h=tid+p*256;
    float u=(t[p]-mean)*rstd*lnw[h]+lnb[h];
    float outv = aum ? u : av[p]*ma;
    mixedB[(size_t)b*4096 + HH + h]=(__bf16)(outv*ma);
  }
}

// ------- factors [mr][1025][1024] fp32 -> factT [mr][h][d] bf16 (d=1..1024) -
__global__ void transpose_factors_k(const float* __restrict__ factors,
                                    __bf16* __restrict__ factT){
  __shared__ float T[64][65];
  int mr = blockIdx.z;
  int d0 = blockIdx.y*64, h0 = blockIdx.x*64;
  int t = threadIdx.x;
  int rr = t>>4, cc = (t&15)*4;
  const float* src = factors + ((size_t)mr*1025 + 1 + d0)*1024 + h0;
#pragma unroll
  for(int q=0;q<4;q++){
    float4 v = *(const float4*)(src + (size_t)(q*16+rr)*1024 + cc);
    T[q*16+rr][cc]=v.x; T[q*16+rr][cc+1]=v.y; T[q*16+rr][cc+2]=v.z; T[q*16+rr][cc+3]=v.w;
  }
  __syncthreads();
  __bf16* dst = factT + ((size_t)mr*1024 + h0)*1024 + d0;
#pragma unroll
  for(int q=0;q<4;q++){
    int hr = q*16 + rr;
    bf16x4 o;
    o[0]=(__bf16)T[cc][hr];   o[1]=(__bf16)T[cc+1][hr];
    o[2]=(__bf16)T[cc+2][hr]; o[3]=(__bf16)T[cc+3][hr];
    *(bf16x4*)(dst + (size_t)hr*1024 + cc) = o;
  }
}

// -------- LMF MFMA GEMM: P[b,r,h] = prod_m (mask[b,m] ? z_m[b,r,h] : 1) -----
// z_m = F0 + mixedB[b,m,:] @ factT[m,r]^T.  128x128 tile, 4 waves, 16x16x32.
__launch_bounds__(256, 2)
__global__ void gemm_lmf_mfma(const __bf16* __restrict__ mixedB,
                              const __bf16* __restrict__ factT,
                              const float* __restrict__ factors,
                              const int* __restrict__ mask,
                              float* __restrict__ P){
  __shared__ __align__(16) __bf16 As[128*32];
  __shared__ __align__(16) __bf16 Bs[128*32];
  __shared__ float Mskf[4][128];
  const int tid = threadIdx.x;
  const int l = tid & 63, w = tid >> 6;
  const int wr = w >> 1, wc = w & 1;
  const int quad = l >> 4, lr16 = l & 15;
  const int row0 = blockIdx.y * 128, col0 = blockIdx.x * 128;
  const int r = blockIdx.z;

  for(int i = tid; i < 512; i += 256){
    int mm = i >> 7, rl = i & 127;
    Mskf[mm][rl] = mask[(row0 + rl)*4 + mm] ? 1.f : 0.f;
  }

  // staging lane mapping (granule-swizzled: granule (row,quad) at idx row*4 + ((quad^(row>>1))&3))
  const int srow = l >> 2;
  const int sq   = (l & 3) ^ ((l >> 3) & 3);

  f32x4 prod[4][4];
  f32x4 onev = {1.f,1.f,1.f,1.f};
  f32x4 zerov = {0.f,0.f,0.f,0.f};
#pragma unroll
  for(int i=0;i<4;i++)
#pragma unroll
    for(int j=0;j<4;j++) prod[i][j] = onev;

  for(int m=0;m<4;m++){
    f32x4 acc[4][4];
#pragma unroll
    for(int i=0;i<4;i++)
#pragma unroll
      for(int j=0;j<4;j++) acc[i][j]=zerov;
    const size_t abase = (size_t)row0*4096 + (size_t)m*1024;
    const size_t bbase = ((size_t)(m*RR + r)*1024 + col0)*1024;
    for(int k0=0;k0<HH;k0+=32){
      __syncthreads();
#pragma unroll
      for(int t=0;t<2;t++){
        int ch = w + 4*t;
        const __bf16* ga = mixedB + abase + (size_t)(ch*16 + srow)*4096 + k0 + sq*8;
        gl_lds16(ga, As + (size_t)(ch*64 + l)*8);
        const __bf16* gb = factT + bbase + (size_t)(ch*16 + srow)*1024 + k0 + sq*8;
        gl_lds16(gb, Bs + (size_t)(ch*64 + l)*8);
      }
      __syncthreads();
      bf16x8 af[4], bg[4];
#pragma unroll
      for(int fi=0;fi<4;fi++){
        int R = wr*64 + fi*16 + lr16;
        af[fi] = *(const bf16x8*)(As + R*32 + ((quad ^ (R>>1)) & 3)*8);
      }
#pragma unroll
      for(int fj=0;fj<4;fj++){
        int N = wc*64 + fj*16 + lr16;
        bg[fj] = *(const bf16x8*)(Bs + N*32 + ((quad ^ (N>>1)) & 3)*8);
      }
#pragma unroll
      for(int fi=0;fi<4;fi++)
#pragma unroll
        for(int fj=0;fj<4;fj++)
          acc[fi][fj] = __builtin_amdgcn_mfma_f32_16x16x32_bf16(af[fi], bg[fj], acc[fi][fj], 0,0,0);
    }
    // epilogue for this m: prod *= (mask ? acc + F0 : 1)
    const float* F0 = factors + (size_t)(m*RR + r)*1025*1024;
    float F0v[4];
#pragma unroll
    for(int fj=0;fj<4;fj++) F0v[fj] = F0[col0 + wc*64 + fj*16 + lr16];
#pragma unroll
    for(int fi=0;fi<4;fi++){
#pragma unroll
      for(int reg=0;reg<4;reg++){
        int rl = wr*64 + fi*16 + quad*4 + reg;
        float mk = Mskf[m][rl];
#pragma unroll
        for(int fj=0;fj<4;fj++){
          float z = acc[fi][fj][reg] + F0v[fj];
          prod[fi][fj][reg] *= (mk != 0.f) ? z : 1.f;
        }
      }
    }
  }
  // store P
#pragma unroll
  for(int fi=0;fi<4;fi++){
#pragma unroll
    for(int reg=0;reg<4;reg++){
      int row = row0 + wr*64 + fi*16 + quad*4 + reg;
#pragma unroll
      for(int fj=0;fj<4;fj++){
        int col = col0 + wc*64 + fj*16 + lr16;
        P[((size_t)row*RR + r)*HH + col] = prod[fi][fj][reg];
      }
    }
  }
}

// -------- fused[b,h] = sum_r rank_w[r]*P[b,r,h] + lmf_bias[h] ---------------
__global__ void fuse_k(const float* __restrict__ P, const float* __restrict__ rank_w,
                       const float* __restrict__ lmf_bias, float* __restrict__ fused){
  size_t i=(size_t)blockIdx.x*256+threadIdx.x;
  int b=(int)(i>>10), h=(int)(i&1023);
  float s=lmf_bias[h];
#pragma unroll
  for(int r=0;r<RR;r++) s += rank_w[r]*P[((size_t)b*RR+r)*HH+h];
  fused[i]=s;
}

// ---------------- row LayerNorm over H=1024 ---------------------------------
__global__ void ln_row_k(const float* __restrict__ X, const float* __restrict__ w,
                         const float* __restrict__ bb, float* __restrict__ Y){
  int b=blockIdx.x, tid=threadIdx.x;
  __shared__ float sc[4];
  const float* x=X+(size_t)b*HH;
  float t[4]; float s=0.f,s2=0.f;
#pragma unroll
  for(int p=0;p<4;p++){ t[p]=x[tid+p*256]; s+=t[p]; s2+=t[p]*t[p]; }
  s=blockSum256(s,sc); s2=blockSum256(s2,sc);
  float mean=s/1024.f, rstd=rsqrtf(s2/1024.f-mean*mean+1e-5f);
#pragma unroll
  for(int p=0;p<4;p++){
    int h=tid+p*256;
    Y[(size_t)b*HH+h]=(t[p]-mean)*rstd*w[h]+bb[h];
  }
}

// ---------------- launch ----------------------------------------------------
extern "C" void kernel_launch(void* const* d_in, const int* in_sizes, int n_in,
                              void* d_out, int out_size, void* d_ws, size_t ws_size,
                              hipStream_t stream) {
  const float* tokens   =(const float*)d_in[0];
  const int*   mask     =(const int*)  d_in[1];
  const float* ln_go_w  =(const float*)d_in[2];
  const float* ln_go_b  =(const float*)d_in[3];
  const float* go_w1    =(const float*)d_in[4];
  const float* go_b1    =(const float*)d_in[5];
  const float* go_w2    =(const float*)d_in[6];
  const float* go_b2    =(const float*)d_in[7];
  const float* ln_ga_w  =(const float*)d_in[8];
  const float* ln_ga_b  =(const float*)d_in[9];
  const float* ga_w1    =(const float*)d_in[10];
  const float* ga_b1    =(const float*)d_in[11];
  const float* ga_w2    =(const float*)d_in[12];
  const float* ga_b2    =(const float*)d_in[13];
  const float* a2o_w    =(const float*)d_in[14];
  const float* o2a_w    =(const float*)d_in[15];
  const float* ln_o_w   =(const float*)d_in[16];
  const float* ln_o_b   =(const float*)d_in[17];
  const float* ln_a_w   =(const float*)d_in[18];
  const float* ln_a_b   =(const float*)d_in[19];
  const float* factors  =(const float*)d_in[20];
  const float* rank_w   =(const float*)d_in[21];
  const float* lmf_bias =(const float*)d_in[22];
  const float* out_ln1_w=(const float*)d_in[23];
  const float* out_ln1_b=(const float*)d_in[24];
  const float* out_w    =(const float*)d_in[25];
  const float* out_b    =(const float*)d_in[26];
  const float* out_ln2_w=(const float*)d_in[27];
  const float* out_ln2_b=(const float*)d_in[28];
  float* out=(float*)d_out;

  char* wsp=(char*)d_ws; size_t off=0;
  auto alloc=[&](size_t bytes)->void*{
    void* p=wsp+off; off=(off+bytes+255)&~(size_t)255; return p;
  };
  float*  stats_go=(float*) alloc((size_t)BB*3*2*4);
  float*  H1      =(float*) alloc((size_t)BB*3*MIDD*4);
  float*  g_go    =(float*) alloc((size_t)BB*3*4);
  float*  a2o     =(float*) alloc((size_t)BB*HH*4);
  __bf16* mixedB  =(__bf16*)alloc((size_t)BB*4*HH*2);
  float*  omean   =(float*) alloc((size_t)BB*HH*4);
  float*  stats_ga=(float*) alloc((size_t)BB*2*4);
  float*  H2      =(float*) alloc((size_t)BB*MIDD*4);
  float*  g_a     =(float*) alloc((size_t)BB*4);
  float*  o2a     =(float*) alloc((size_t)BB*HH*4);
  __bf16* factT   =(__bf16*)alloc((size_t)4*RR*HH*HH*2);
  float*  P       =(float*) alloc((size_t)BB*RR*HH*4);
  float*  fused   =(float*) alloc((size_t)BB*HH*4);
  float*  hbuf    =(float*) alloc((size_t)BB*HH*4);

  // 0) factors -> bf16 transposed (independent of everything else)
  transpose_factors_k<<<dim3(16,16,40),256,0,stream>>>(factors,factT);
  // 1) gate-others LN stats
  stats_go_k<<<BB*3,256,0,stream>>>(tokens,mask,stats_go);
  // 2) a2o = audio @ a2o_w^T
  gemm_nt_k<0><<<dim3(HH/64,BB/64),256,0,stream>>>(tokens+HH,4*HH,a2o_w,nullptr,a2o,HH,HH);
  // 3) H1 = gelu(LN(feat_go) @ go_w1^T + go_b1)
  gemm_gate_k<0><<<dim3(MIDD/64,(BB*3)/64),256,0,stream>>>(tokens,mask,omean,stats_go,
                                                           ln_go_w,ln_go_b,go_w1,go_b1,H1);
  // 4) g_go = sigmoid(H1 . go_w2 + go_b2)
  gate_reduce_k<<<BB*3,64,0,stream>>>(H1,go_w2,go_b2,g_go,MIDD);
  // 5) others_new -> mixedB slots {0,2,3}; others_mean
  others_k<<<BB,256,0,stream>>>(tokens,mask,g_go,a2o,ln_o_w,ln_o_b,mixedB,omean);
  // 6) gate-audio LN stats
  stats_ga_k<<<BB,256,0,stream>>>(tokens,omean,stats_ga);
  // 7) H2 = gelu(LN(feat_ga) @ ga_w1^T + ga_b1)
  gemm_gate_k<1><<<dim3(MIDD/64,BB/64),256,0,stream>>>(tokens,mask,omean,stats_ga,
                                                       ln_ga_w,ln_ga_b,ga_w1,ga_b1,H2);
  // 8) g_a
  gate_reduce_k<<<BB,64,0,stream>>>(H2,ga_w2,ga_b2,g_a,MIDD);
  // 9) o2a = others_mean @ o2a_w^T
  gemm_nt_k<0><<<dim3(HH/64,BB/64),256,0,stream>>>(omean,HH,o2a_w,nullptr,o2a,HH,HH);
  // 10) mixed_audio -> mixedB slot 1
  audio_k<<<BB,256,0,stream>>>(tokens,mask,g_a,o2a,ln_a_w,ln_a_b,mixedB);
  // 11) LMF rank product (MFMA, all m fused, P write-once)
  gemm_lmf_mfma<<<dim3(HH/128,BB/128,RR),256,0,stream>>>(mixedB,factT,factors,mask,P);
  // 12) fused = sum_r rank_w[r]*P + lmf_bias
  fuse_k<<<(BB*HH)/256,256,0,stream>>>(P,rank_w,lmf_bias,fused);
  // 13) h = LN(fused)
  ln_row_k<<<BB,256,0,stream>>>(fused,out_ln1_w,out_ln1_b,hbuf);
  // 14) h = gelu(h @ out_w^T + out_b)
  gemm_nt_k<1><<<dim3(HH/64,BB/64),256,0,stream>>>(hbuf,HH,out_w,out_b,fused,HH,HH);
  // 15) out = LN(h)
  ln_row_k<<<BB,256,0,stream>>>(fused,out_ln2_w,out_ln2_b,out);
}

// Round 3
// 1425.080 us; speedup vs baseline: 4.1483x; 1.6260x over previous
//
#include <hip/hip_runtime.h>
#include <math.h>

#define BB 4096
#define HH 1024
#define RR 10
#define MIDD 512
#define D3 3072

typedef __bf16 bf16x8 __attribute__((ext_vector_type(8)));
typedef __bf16 bf16x4 __attribute__((ext_vector_type(4)));
typedef float f32x4 __attribute__((ext_vector_type(4)));

// ---------------- reduction helpers ----------------
__device__ __forceinline__ float waveSum(float v){
#pragma unroll
  for(int o=32;o>0;o>>=1) v += __shfl_down(v,o,64);
  return v;
}
__device__ __forceinline__ float blockSum256(float v, float* sc){
  v = waveSum(v);
  __syncthreads();
  if((threadIdx.x & 63)==0) sc[threadIdx.x>>6] = v;
  __syncthreads();
  return sc[0]+sc[1]+sc[2]+sc[3];
}
__device__ __forceinline__ float gelu_f(float x){
  return 0.5f*x*(1.0f+erff(x*0.70710678118654752f));
}
__device__ __forceinline__ void gl_lds16(const void* g, void* lds){
  __builtin_amdgcn_global_load_lds((const __attribute__((address_space(1))) unsigned int*)g,
                                   (__attribute__((address_space(3))) unsigned int*)lds,
                                   16, 0, 0);
}

// ---------- weight convert: 5 fp32 matrices -> bf16, one launch -------------
__global__ void convw_k(const float* __restrict__ s0, __bf16* __restrict__ d0, int n0,
                        const float* __restrict__ s1, __bf16* __restrict__ d1, int n1,
                        const float* __restrict__ s2, __bf16* __restrict__ d2, int n2,
                        const float* __restrict__ s3, __bf16* __restrict__ d3, int n3,
                        const float* __restrict__ s4, __bf16* __restrict__ d4, int n4){
  long i = ((long)blockIdx.x*256 + threadIdx.x)*4;
  const float* s; __bf16* d;
  if(i<n0){ s=s0; d=d0; }
  else { i-=n0; if(i<n1){ s=s1; d=d1; }
  else { i-=n1; if(i<n2){ s=s2; d=d2; }
  else { i-=n2; if(i<n3){ s=s3; d=d3; }
  else { i-=n3; if(i>=n4) return; s=s4; d=d4; } } } }
  float4 v=*(const float4*)(s+i);
  bf16x4 o; o[0]=(__bf16)v.x; o[1]=(__bf16)v.y; o[2]=(__bf16)v.z; o[3]=(__bf16)v.w;
  *(bf16x4*)(d+i)=o;
}

// ------- gate-others features: LN([t,s,|t-s|]) -> bf16 rows (B*3 x 3072) ----
// also writes audioB (bf16 copy of tokens[:,1,:]) from the j==0 blocks
__global__ void feat_go_k(const float* __restrict__ tokens, const int* __restrict__ mask,
                          const float* __restrict__ lnw, const float* __restrict__ lnb,
                          __bf16* __restrict__ featGo, __bf16* __restrict__ audioB){
  int row=blockIdx.x; int b=row/3; int j=row-b*3; int oj=(j==0)?0:(j+1);
  const float* to=tokens+((size_t)b*4+oj)*HH;
  const float* ta=tokens+((size_t)b*4+1)*HH;
  float mo = mask[b*4+oj]?1.f:0.f;
  int tid=threadIdx.x;
  __shared__ float sc[4];
  float ov[4], av[4], dv[4]; float s=0.f,s2=0.f;
#pragma unroll
  for(int p=0;p<4;p++){
    int h=tid+p*256;
    float o=to[h]*mo, a=ta[h], d=fabsf(o-a);
    ov[p]=o; av[p]=a; dv[p]=d;
    s+=o+a+d; s2+=o*o+a*a+d*d;
  }
  s=blockSum256(s,sc); s2=blockSum256(s2,sc);
  float mean=s/(float)D3, rstd=rsqrtf(s2/(float)D3-mean*mean+1e-5f);
  __bf16* fr = featGo + (size_t)row*D3;
#pragma unroll
  for(int p=0;p<4;p++){
    int h=tid+p*256;
    fr[h]       =(__bf16)((ov[p]-mean)*rstd*lnw[h]+lnb[h]);
    fr[1024+h]  =(__bf16)((av[p]-mean)*rstd*lnw[1024+h]+lnb[1024+h]);
    fr[2048+h]  =(__bf16)((dv[p]-mean)*rstd*lnw[2048+h]+lnb[2048+h]);
    if(j==0) audioB[(size_t)b*HH+h]=(__bf16)av[p];
  }
}

// ------- gate-audio features: LN([audio, omean, |diff|]) -> bf16 (B x 3072) -
__global__ void feat_ga_k(const float* __restrict__ tokens, const float* __restrict__ omean,
                          const float* __restrict__ lnw, const float* __restrict__ lnb,
                          __bf16* __restrict__ featGa){
  int b=blockIdx.x; int tid=threadIdx.x;
  const float* ta=tokens+((size_t)b*4+1)*HH;
  const float* so=omean+(size_t)b*HH;
  __shared__ float sc[4];
  float tv[4], sv[4], dv[4]; float s=0.f,s2=0.f;
#pragma unroll
  for(int p=0;p<4;p++){
    int h=tid+p*256;
    float a=ta[h], o=so[h], d=fabsf(a-o);
    tv[p]=a; sv[p]=o; dv[p]=d;
    s+=a+o+d; s2+=a*a+o*o+d*d;
  }
  s=blockSum256(s,sc); s2=blockSum256(s2,sc);
  float mean=s/(float)D3, rstd=rsqrtf(s2/(float)D3-mean*mean+1e-5f);
  __bf16* fr = featGa + (size_t)b*D3;
#pragma unroll
  for(int p=0;p<4;p++){
    int h=tid+p*256;
    fr[h]     =(__bf16)((tv[p]-mean)*rstd*lnw[h]+lnb[h]);
    fr[1024+h]=(__bf16)((sv[p]-mean)*rstd*lnw[1024+h]+lnb[1024+h]);
    fr[2048+h]=(__bf16)((dv[p]-mean)*rstd*lnw[2048+h]+lnb[2048+h]);
  }
}

// -------- unified bf16 MFMA NT GEMM: C = act(A @ B^T [+ bias]) --------------
// A: M x K bf16 (lda), B: N x K bf16 (ldb), C: M x N fp32 (ldc).
// 128x128 tile, BK=32, 4 waves, 16x16x32 MFMA, swizzled LDS granules.
template<int ACT>
__launch_bounds__(256, 2)
__global__ void gemm_nt_mfma(const __bf16* __restrict__ A, int lda,
                             const __bf16* __restrict__ Bm, int ldb,
                             const float* __restrict__ bias,
                             float* __restrict__ C, int ldc, int K){
  __shared__ __align__(16) __bf16 As[128*32];
  __shared__ __align__(16) __bf16 Bs[128*32];
  const int tid=threadIdx.x, l=tid&63, w=tid>>6;
  const int wr=w>>1, wc=w&1;
  const int quad=l>>4, lr16=l&15;
  const int row0=blockIdx.y*128, col0=blockIdx.x*128;
  const int srow=l>>2, sq=(l&3)^((l>>3)&3);
  f32x4 acc[4][4];
  f32x4 zerov={0.f,0.f,0.f,0.f};
#pragma unroll
  for(int i=0;i<4;i++)
#pragma unroll
    for(int j=0;j<4;j++) acc[i][j]=zerov;
  for(int k0=0;k0<K;k0+=32){
    __syncthreads();
#pragma unroll
    for(int t=0;t<2;t++){
      int ch=w+4*t;
      gl_lds16(A  + (size_t)(row0+ch*16+srow)*lda + k0 + sq*8, As + (size_t)(ch*64+l)*8);
      gl_lds16(Bm + (size_t)(col0+ch*16+srow)*ldb + k0 + sq*8, Bs + (size_t)(ch*64+l)*8);
    }
    __syncthreads();
    bf16x8 af[4], bg[4];
#pragma unroll
    for(int fi=0;fi<4;fi++){
      int R=wr*64+fi*16+lr16;
      af[fi]=*(const bf16x8*)(As + R*32 + ((quad^(R>>1))&3)*8);
    }
#pragma unroll
    for(int fj=0;fj<4;fj++){
      int N=wc*64+fj*16+lr16;
      bg[fj]=*(const bf16x8*)(Bs + N*32 + ((quad^(N>>1))&3)*8);
    }
#pragma unroll
    for(int fi=0;fi<4;fi++)
#pragma unroll
      for(int fj=0;fj<4;fj++)
        acc[fi][fj]=__builtin_amdgcn_mfma_f32_16x16x32_bf16(af[fi],bg[fj],acc[fi][fj],0,0,0);
  }
  float bv[4];
#pragma unroll
  for(int fj=0;fj<4;fj++) bv[fj] = (ACT==1)? bias[col0+wc*64+fj*16+lr16] : 0.f;
#pragma unroll
  for(int fi=0;fi<4;fi++){
#pragma unroll
    for(int reg=0;reg<4;reg++){
      int row=row0+wr*64+fi*16+quad*4+reg;
#pragma unroll
      for(int fj=0;fj<4;fj++){
        int col=col0+wc*64+fj*16+lr16;
        float v=acc[fi][fj][reg];
        if(ACT==1) v=gelu_f(v+bv[fj]);
        C[(size_t)row*ldc+col]=v;
      }
    }
  }
}

// ---------------- gate reduce: g = sigmoid(H . w2 + b2) ---------------------
__global__ void gate_reduce_k(const float* __restrict__ Hx, const float* __restrict__ w2,
                              const float* __restrict__ b2, float* __restrict__ g, int cols){
  int row=blockIdx.x;
  float s=0.f;
  for(int c=threadIdx.x;c<cols;c+=64) s += Hx[(size_t)row*cols+c]*w2[c];
  s=waveSum(s);
  if(threadIdx.x==0) g[row]=1.f/(1.f+expf(-(s+b2[0])));
}

// ------- others_new (into mixedB slots 0,2,3) + others_mean (f32 + bf16) ----
__global__ void others_k(const float* __restrict__ tokens, const int* __restrict__ mask,
                         const float* __restrict__ g, const float* __restrict__ a2o,
                         const float* __restrict__ lnw, const float* __restrict__ lnb,
                         __bf16* __restrict__ mixedB, float* __restrict__ omean,
                         __bf16* __restrict__ omeanB){
  int b=blockIdx.x, tid=threadIdx.x;
  __shared__ float sc[4];
  float ma = mask[b*4+1]?1.f:0.f;
  float a2[4];
#pragma unroll
  for(int p=0;p<4;p++) a2[p]=a2o[(size_t)b*HH+tid+p*256];
  float sum[4]={0,0,0,0}; float cnt=0.f;
  for(int j=0;j<3;j++){
    int oj=(j==0)?0:(j+1);
    float mo=mask[b*4+oj]?1.f:0.f; cnt+=mo;
    float gv=g[b*3+j];
    float t[4], ov[4]; float s=0.f,s2=0.f;
#pragma unroll
    for(int p=0;p<4;p++){
      int h=tid+p*256;
      float o=tokens[((size_t)b*4+oj)*HH+h]*mo;
      ov[p]=o; t[p]=o+gv*a2[p];
      s+=t[p]; s2+=t[p]*t[p];
    }
    s=blockSum256(s,sc); s2=blockSum256(s2,sc);
    float mean=s/1024.f, rstd=rsqrtf(s2/1024.f-mean*mean+1e-5f);
    float pv=mo*ma;
#pragma unroll
    for(int p=0;p<4;p++){
      int h=tid+p*256;
      float upd=(t[p]-mean)*rstd*lnw[h]+lnb[h];
      float on=((pv>0.5f)?upd:ov[p])*mo;
      mixedB[(size_t)b*4096 + (size_t)oj*HH + h]=(__bf16)on;
      sum[p]+=on*mo;
    }
  }
  float denom=fmaxf(cnt,1.f);
#pragma unroll
  for(int p=0;p<4;p++){
    float v=sum[p]/denom;
    omean[(size_t)b*HH+tid+p*256]=v;
    omeanB[(size_t)b*HH+tid+p*256]=(__bf16)v;
  }
}

// ---------------- mixed_audio (into mixedB slot 1, bf16) --------------------
__global__ void audio_k(const float* __restrict__ tokens, const int* __restrict__ mask,
                        const float* __restrict__ g_a, const float* __restrict__ o2a,
                        const float* __restrict__ lnw, const float* __restrict__ lnb,
                        __bf16* __restrict__ mixedB){
  int b=blockIdx.x, tid=threadIdx.x;
  __shared__ float sc[4];
  int ma_i=mask[b*4+1];
  int any = mask[b*4+0]|mask[b*4+2]|mask[b*4+3];
  bool aum = (ma_i!=0) && (any!=0);
  float ma = ma_i?1.f:0.f;
  float gv=g_a[b];
  const float* ta = tokens + ((size_t)b*4+1)*HH;
  float av[4], t[4]; float s=0.f,s2=0.f;
#pragma unroll
  for(int p=0;p<4;p++){
    int h=tid+p*256;
    av[p]=ta[h];
    t[p]=av[p]+gv*o2a[(size_t)b*HH+h];
    s+=t[p]; s2+=t[p]*t[p];
  }
  s=blockSum256(s,sc); s2=blockSum256(s2,sc);
  float mean=s/1024.f, rstd=rsqrtf(s2/1024.f-mean*mean+1e-5f);
#pragma unroll
  for(int p=0;p<4;p++){
    int h=tid+p*256;
    float u=(t[p]-mean)*rstd*lnw[h]+lnb[h];
    float outv = aum ? u : av[p]*ma;
    mixedB[(size_t)b*4096 + HH + h]=(__bf16)(outv*ma);
  }
}

// ------- factors [mr][1025][1024] fp32 -> factT [mr][h][d] bf16 (d=1..1024) -
__global__ void transpose_factors_k(const float* __restrict__ factors,
                                    __bf16* __restrict__ factT){
  __shared__ float T[64][65];
  int mr = blockIdx.z;
  int d0 = blockIdx.y*64, h0 = blockIdx.x*64;
  int t = threadIdx.x;
  int rr = t>>4, cc = (t&15)*4;
  const float* src = factors + ((size_t)mr*1025 + 1 + d0)*1024 + h0;
#pragma unroll
  for(int q=0;q<4;q++){
    float4 v = *(const float4*)(src + (size_t)(q*16+rr)*1024 + cc);
    T[q*16+rr][cc]=v.x; T[q*16+rr][cc+1]=v.y; T[q*16+rr][cc+2]=v.z; T[q*16+rr][cc+3]=v.w;
  }
  __syncthreads();
  __bf16* dst = factT + ((size_t)mr*1024 + h0)*1024 + d0;
#pragma unroll
  for(int q=0;q<4;q++){
    int hr = q*16 + rr;
    bf16x4 o;
    o[0]=(__bf16)T[cc][hr];   o[1]=(__bf16)T[cc+1][hr];
    o[2]=(__bf16)T[cc+2][hr]; o[3]=(__bf16)T[cc+3][hr];
    *(bf16x4*)(dst + (size_t)hr*1024 + cc) = o;
  }
}

// -------- LMF MFMA GEMM: P[b,r,h] = prod_m (mask[b,m] ? z_m[b,r,h] : 1) -----
__launch_bounds__(256, 2)
__global__ void gemm_lmf_mfma(const __bf16* __restrict__ mixedB,
                              const __bf16* __restrict__ factT,
                              const float* __restrict__ factors,
                              const int* __restrict__ mask,
                              float* __restrict__ P){
  __shared__ __align__(16) __bf16 As[128*32];
  __shared__ __align__(16) __bf16 Bs[128*32];
  __shared__ float Mskf[4][128];
  const int tid = threadIdx.x;
  const int l = tid & 63, w = tid >> 6;
  const int wr = w >> 1, wc = w & 1;
  const int quad = l >> 4, lr16 = l & 15;
  const int row0 = blockIdx.y * 128, col0 = blockIdx.x * 128;
  const int r = blockIdx.z;

  for(int i = tid; i < 512; i += 256){
    int mm = i >> 7, rl = i & 127;
    Mskf[mm][rl] = mask[(row0 + rl)*4 + mm] ? 1.f : 0.f;
  }
  const int srow = l >> 2;
  const int sq   = (l & 3) ^ ((l >> 3) & 3);

  f32x4 prod[4][4];
  f32x4 onev = {1.f,1.f,1.f,1.f};
  f32x4 zerov = {0.f,0.f,0.f,0.f};
#pragma unroll
  for(int i=0;i<4;i++)
#pragma unroll
    for(int j=0;j<4;j++) prod[i][j] = onev;

  for(int m=0;m<4;m++){
    f32x4 acc[4][4];
#pragma unroll
    for(int i=0;i<4;i++)
#pragma unroll
      for(int j=0;j<4;j++) acc[i][j]=zerov;
    const size_t abase = (size_t)row0*4096 + (size_t)m*1024;
    const size_t bbase = ((size_t)(m*RR + r)*1024 + col0)*1024;
    for(int k0=0;k0<HH;k0+=32){
      __syncthreads();
#pragma unroll
      for(int t=0;t<2;t++){
        int ch = w + 4*t;
        const __bf16* ga = mixedB + abase + (size_t)(ch*16 + srow)*4096 + k0 + sq*8;
        gl_lds16(ga, As + (size_t)(ch*64 + l)*8);
        const __bf16* gb = factT + bbase + (size_t)(ch*16 + srow)*1024 + k0 + sq*8;
        gl_lds16(gb, Bs + (size_t)(ch*64 + l)*8);
      }
      __syncthreads();
      bf16x8 af[4], bg[4];
#pragma unroll
      for(int fi=0;fi<4;fi++){
        int R = wr*64 + fi*16 + lr16;
        af[fi] = *(const bf16x8*)(As + R*32 + ((quad ^ (R>>1)) & 3)*8);
      }
#pragma unroll
      for(int fj=0;fj<4;fj++){
        int N = wc*64 + fj*16 + lr16;
        bg[fj] = *(const bf16x8*)(Bs + N*32 + ((quad ^ (N>>1)) & 3)*8);
      }
#pragma unroll
      for(int fi=0;fi<4;fi++)
#pragma unroll
        for(int fj=0;fj<4;fj++)
          acc[fi][fj] = __builtin_amdgcn_mfma_f32_16x16x32_bf16(af[fi], bg[fj], acc[fi][fj], 0,0,0);
    }
    const float* F0 = factors + (size_t)(m*RR + r)*1025*1024;
    float F0v[4];
#pragma unroll
    for(int fj=0;fj<4;fj++) F0v[fj] = F0[col0 + wc*64 + fj*16 + lr16];
#pragma unroll
    for(int fi=0;fi<4;fi++){
#pragma unroll
      for(int reg=0;reg<4;reg++){
        int rl = wr*64 + fi*16 + quad*4 + reg;
        float mk = Mskf[m][rl];
#pragma unroll
        for(int fj=0;fj<4;fj++){
          float z = acc[fi][fj][reg] + F0v[fj];
          prod[fi][fj][reg] *= (mk != 0.f) ? z : 1.f;
        }
      }
    }
  }
#pragma unroll
  for(int fi=0;fi<4;fi++){
#pragma unroll
    for(int reg=0;reg<4;reg++){
      int row = row0 + wr*64 + fi*16 + quad*4 + reg;
#pragma unroll
      for(int fj=0;fj<4;fj++){
        int col = col0 + wc*64 + fj*16 + lr16;
        P[((size_t)row*RR + r)*HH + col] = prod[fi][fj][reg];
      }
    }
  }
}

// -------- fused[b,h] = sum_r rank_w[r]*P[b,r,h] + lmf_bias[h] ---------------
__global__ void fuse_k(const float* __restrict__ P, const float* __restrict__ rank_w,
                       const float* __restrict__ lmf_bias, float* __restrict__ fused){
  size_t i=(size_t)blockIdx.x*256+threadIdx.x;
  int b=(int)(i>>10), h=(int)(i&1023);
  float s=lmf_bias[h];
#pragma unroll
  for(int r=0;r<RR;r++) s += rank_w[r]*P[((size_t)b*RR+r)*HH+h];
  fused[i]=s;
}

// ---------------- row LayerNorm over H=1024 (fp32 out) ----------------------
__global__ void ln_row_k(const float* __restrict__ X, const float* __restrict__ w,
                         const float* __restrict__ bb, float* __restrict__ Y){
  int b=blockIdx.x, tid=threadIdx.x;
  __shared__ float sc[4];
  const float* x=X+(size_t)b*HH;
  float t[4]; float s=0.f,s2=0.f;
#pragma unroll
  for(int p=0;p<4;p++){ t[p]=x[tid+p*256]; s+=t[p]; s2+=t[p]*t[p]; }
  s=blockSum256(s,sc); s2=blockSum256(s2,sc);
  float mean=s/1024.f, rstd=rsqrtf(s2/1024.f-mean*mean+1e-5f);
#pragma unroll
  for(int p=0;p<4;p++){
    int h=tid+p*256;
    Y[(size_t)b*HH+h]=(t[p]-mean)*rstd*w[h]+bb[h];
  }
}
// ---------------- row LayerNorm over H=1024 (bf16 out) ----------------------
__global__ void ln_row_bf16_k(const float* __restrict__ X, const float* __restrict__ w,
                              const float* __restrict__ bb, __bf16* __restrict__ Y){
  int b=blockIdx.x, tid=threadIdx.x;
  __shared__ float sc[4];
  const float* x=X+(size_t)b*HH;
  float t[4]; float s=0.f,s2=0.f;
#pragma unroll
  for(int p=0;p<4;p++){ t[p]=x[tid+p*256]; s+=t[p]; s2+=t[p]*t[p]; }
  s=blockSum256(s,sc); s2=blockSum256(s2,sc);
  float mean=s/1024.f, rstd=rsqrtf(s2/1024.f-mean*mean+1e-5f);
#pragma unroll
  for(int p=0;p<4;p++){
    int h=tid+p*256;
    Y[(size_t)b*HH+h]=(__bf16)((t[p]-mean)*rstd*w[h]+bb[h]);
  }
}

// ---------------- launch ----------------------------------------------------
extern "C" void kernel_launch(void* const* d_in, const int* in_sizes, int n_in,
                              void* d_out, int out_size, void* d_ws, size_t ws_size,
                              hipStream_t stream) {
  const float* tokens   =(const float*)d_in[0];
  const int*   mask     =(const int*)  d_in[1];
  const float* ln_go_w  =(const float*)d_in[2];
  const float* ln_go_b  =(const float*)d_in[3];
  const float* go_w1    =(const float*)d_in[4];
  const float* go_b1    =(const float*)d_in[5];
  const float* go_w2    =(const float*)d_in[6];
  const float* go_b2    =(const float*)d_in[7];
  const float* ln_ga_w  =(const float*)d_in[8];
  const float* ln_ga_b  =(const float*)d_in[9];
  const float* ga_w1    =(const float*)d_in[10];
  const float* ga_b1    =(const float*)d_in[11];
  const float* ga_w2    =(const float*)d_in[12];
  const float* ga_b2    =(const float*)d_in[13];
  const float* a2o_w    =(const float*)d_in[14];
  const float* o2a_w    =(const float*)d_in[15];
  const float* ln_o_w   =(const float*)d_in[16];
  const float* ln_o_b   =(const float*)d_in[17];
  const float* ln_a_w   =(const float*)d_in[18];
  const float* ln_a_b   =(const float*)d_in[19];
  const float* factors  =(const float*)d_in[20];
  const float* rank_w   =(const float*)d_in[21];
  const float* lmf_bias =(const float*)d_in[22];
  const float* out_ln1_w=(const float*)d_in[23];
  const float* out_ln1_b=(const float*)d_in[24];
  const float* out_w    =(const float*)d_in[25];
  const float* out_b    =(const float*)d_in[26];
  const float* out_ln2_w=(const float*)d_in[27];
  const float* out_ln2_b=(const float*)d_in[28];
  float* out=(float*)d_out;

  char* wsp=(char*)d_ws; size_t off=0;
  auto alloc=[&](size_t bytes)->void*{
    void* p=wsp+off; off=(off+bytes+255)&~(size_t)255; return p;
  };
  float*  P       =(float*) alloc((size_t)BB*RR*HH*4);      // 168 MB
  __bf16* factT   =(__bf16*)alloc((size_t)4*RR*HH*HH*2);    // 84 MB
  float*  H1      =(float*) alloc((size_t)BB*3*MIDD*4);
  float*  g_go    =(float*) alloc((size_t)BB*3*4);
  float*  a2o     =(float*) alloc((size_t)BB*HH*4);
  __bf16* mixedB  =(__bf16*)alloc((size_t)BB*4*HH*2);
  float*  omean   =(float*) alloc((size_t)BB*HH*4);
  __bf16* omeanB  =(__bf16*)alloc((size_t)BB*HH*2);
  __bf16* audioB  =(__bf16*)alloc((size_t)BB*HH*2);
  float*  H2      =(float*) alloc((size_t)BB*MIDD*4);
  float*  g_a     =(float*) alloc((size_t)BB*4);
  float*  o2a     =(float*) alloc((size_t)BB*HH*4);
  float*  fused   =(float*) alloc((size_t)BB*HH*4);
  __bf16* hbufB   =(__bf16*)alloc((size_t)BB*HH*2);
  __bf16* go_w1B  =(__bf16*)alloc((size_t)MIDD*D3*2);
  __bf16* ga_w1B  =(__bf16*)alloc((size_t)MIDD*D3*2);
  __bf16* a2o_wB  =(__bf16*)alloc((size_t)HH*HH*2);
  __bf16* o2a_wB  =(__bf16*)alloc((size_t)HH*HH*2);
  __bf16* out_wB  =(__bf16*)alloc((size_t)HH*HH*2);
  // feat buffers alias P (dead before lmf writes P): featGo 75.5MB + featGa 25.2MB < 168MB
  __bf16* featGo  =(__bf16*)P;
  __bf16* featGa  =(__bf16*)((char*)P + (size_t)BB*3*D3*2);

  // 0) weight converts + factor transpose (independent)
  {
    int n0=MIDD*D3, n1=MIDD*D3, n2=HH*HH, n3=HH*HH, n4=HH*HH;
    int total4=(n0+n1+n2+n3+n4)/4;
    convw_k<<<(total4+255)/256,256,0,stream>>>(go_w1,go_w1B,n0, ga_w1,ga_w1B,n1,
                                               a2o_w,a2o_wB,n2, o2a_w,o2a_wB,n3,
                                               out_w,out_wB,n4);
  }
  transpose_factors_k<<<dim3(16,16,40),256,0,stream>>>(factors,factT);
  // 1) gate-others features (bf16, LN applied) + audioB
  feat_go_k<<<BB*3,256,0,stream>>>(tokens,mask,ln_go_w,ln_go_b,featGo,audioB);
  // 2) a2o = audio @ a2o_w^T   (bf16 MFMA)
  gemm_nt_mfma<0><<<dim3(8,32),256,0,stream>>>(audioB,HH,a2o_wB,HH,nullptr,a2o,HH,HH);
  // 3) H1 = gelu(featGo @ go_w1^T + go_b1)
  gemm_nt_mfma<1><<<dim3(4,96),256,0,stream>>>(featGo,D3,go_w1B,D3,go_b1,H1,MIDD,D3);
  // 4) g_go
  gate_reduce_k<<<BB*3,64,0,stream>>>(H1,go_w2,go_b2,g_go,MIDD);
  // 5) others_new -> mixedB {0,2,3}; others_mean (f32+bf16)
  others_k<<<BB,256,0,stream>>>(tokens,mask,g_go,a2o,ln_o_w,ln_o_b,mixedB,omean,omeanB);
  // 6) gate-audio features
  feat_ga_k<<<BB,256,0,stream>>>(tokens,omean,ln_ga_w,ln_ga_b,featGa);
  // 7) H2 = gelu(featGa @ ga_w1^T + ga_b1)
  gemm_nt_mfma<1><<<dim3(4,32),256,0,stream>>>(featGa,D3,ga_w1B,D3,ga_b1,H2,MIDD,D3);
  // 8) g_a
  gate_reduce_k<<<BB,64,0,stream>>>(H2,ga_w2,ga_b2,g_a,MIDD);
  // 9) o2a = others_mean @ o2a_w^T
  gemm_nt_mfma<0><<<dim3(8,32),256,0,stream>>>(omeanB,HH,o2a_wB,HH,nullptr,o2a,HH,HH);
  // 10) mixed_audio -> mixedB slot 1
  audio_k<<<BB,256,0,stream>>>(tokens,mask,g_a,o2a,ln_a_w,ln_a_b,mixedB);
  // 11) LMF rank product (MFMA, all m fused, P write-once)
  gemm_lmf_mfma<<<dim3(HH/128,BB/128,RR),256,0,stream>>>(mixedB,factT,factors,mask,P);
  // 12) fused = sum_r rank_w[r]*P + lmf_bias
  fuse_k<<<(BB*HH)/256,256,0,stream>>>(P,rank_w,lmf_bias,fused);
  // 13) hbufB = LN(fused) as bf16
  ln_row_bf16_k<<<BB,256,0,stream>>>(fused,out_ln1_w,out_ln1_b,hbufB);
  // 14) fused = gelu(hbufB @ out_w^T + out_b)
  gemm_nt_mfma<1><<<dim3(8,32),256,0,stream>>>(hbufB,HH,out_wB,HH,out_b,fused,HH,HH);
  // 15) out = LN(fused)
  ln_row_k<<<BB,256,0,stream>>>(fused,out_ln2_w,out_ln2_b,out);
}